// Round 10
// baseline (264.456 us; speedup 1.0000x reference)
//
#include <hip/hip_runtime.h>
#include <hip/hip_bf16.h>
#include <stdint.h>

#define NN 40000
#define NE 640000
#define ND 128
#define ED 64
#define OD 128
#define KM 192   // ND + ED
#define KA 256   // ND + OD
#define NB 40    // scan blocks (40*1024 >= NN)

typedef __attribute__((ext_vector_type(8))) short bf16x8;
typedef __attribute__((ext_vector_type(4))) float f32x4;
typedef __attribute__((ext_vector_type(4))) unsigned short us4;

__device__ __forceinline__ uint32_t pkbf2(float a, float b) {
    __hip_bfloat162 h = __float22bfloat162_rn(make_float2(a, b));
    union { __hip_bfloat162 h; uint32_t u; } cv; cv.h = h; return cv.u;
}
__device__ __forceinline__ unsigned short f2bf1(float f) {
    __hip_bfloat16 h = __float2bfloat16(f);
    union { __hip_bfloat16 h; unsigned short u; } cv; cv.h = h; return cv.u;
}
__device__ __forceinline__ us4 pk4(float4 v) {
    union { uint2 u; us4 s; } cv;
    cv.u.x = pkbf2(v.x, v.y);
    cv.u.y = pkbf2(v.z, v.w);
    return cv.s;
}
__device__ __forceinline__ bf16x8 pk8(float4 a, float4 b) {
    union { uint4 u; bf16x8 s; } cv;
    cv.u.x = pkbf2(a.x, a.y); cv.u.y = pkbf2(a.z, a.w);
    cv.u.z = pkbf2(b.x, b.y); cv.u.w = pkbf2(b.z, b.w);
    return cv.s;
}
__device__ __forceinline__ float b2f(unsigned short u) {
    union { uint32_t u; float f; } v; v.u = ((uint32_t)u) << 16; return v.f;
}

// ---------------- CSR build ----------------
// hist + zero hn (fused)
__global__ __launch_bounds__(256) void hist_kernel(
    const int* __restrict__ dst, int* __restrict__ cnt, float4* __restrict__ hnz)
{
    int e = blockIdx.x * blockDim.x + threadIdx.x;
    if (e < NE) atomicAdd(&cnt[dst[e]], 1);
    #pragma unroll
    for (int k = 0; k < 2; ++k) {
        int j = e + k * (NE);
        if (j < NN * OD / 4) hnz[j] = make_float4(0.f, 0.f, 0.f, 0.f);
    }
}

// in-place per-block exclusive scan of cur[1024] chunk; bsum[b] = block total
__global__ __launch_bounds__(1024) void scanA_kernel(
    int* __restrict__ cur, int* __restrict__ bsum)
{
    __shared__ int wsum[16];
    const int t = threadIdx.x, b = blockIdx.x;
    const int idx = b * 1024 + t;
    int v = (idx < NN) ? cur[idx] : 0;
    int x = v;
    #pragma unroll
    for (int d = 1; d < 64; d <<= 1) {
        int y = __shfl_up(x, d, 64);
        if ((t & 63) >= d) x += y;
    }
    const int wid = t >> 6;
    if ((t & 63) == 63) wsum[wid] = x;
    __syncthreads();
    if (t < 16) {
        int s = wsum[t];
        #pragma unroll
        for (int d = 1; d < 16; d <<= 1) {
            int y = __shfl_up(s, d, 64);
            if (t >= d) s += y;
        }
        wsum[t] = s;
    }
    __syncthreads();
    int incl = x + (wid > 0 ? wsum[wid - 1] : 0);
    if (idx < NN) cur[idx] = incl - v;
    if (t == 1023) bsum[b] = incl;
}

// add prefix of block sums; ALSO convert Wa -> bf16 (Wab)
__global__ __launch_bounds__(1024) void scanC_kernel(
    int* __restrict__ cur, const int* __restrict__ bsum,
    const float* __restrict__ Wa, unsigned short* __restrict__ Wab)
{
    __shared__ int sboff;
    const int t = threadIdx.x, b = blockIdx.x;
    if (t < 64) {
        int v = (t < b) ? bsum[t] : 0;
        #pragma unroll
        for (int d = 32; d > 0; d >>= 1) v += __shfl_down(v, d, 64);
        if (t == 0) sboff = v;
    }
    const int gidx = b * 1024 + t;
    if (gidx < OD * KA) Wab[gidx] = f2bf1(Wa[gidx]);
    __syncthreads();
    if (gidx < NN) cur[gidx] += sboff;
}

// ---------------- fused scatter + proj (grid-partitioned) ----------------
// blocks [0, 2500): scatter edges into dst-sorted tri2 = (e, src | dst<<16)
// blocks [2500, 3750): proj P = node @ Wn^T + bm (bf16), register-B
#define PT 32
#define SCB 2500

__global__ __launch_bounds__(256, 4) void scatterproj_kernel(
    const int* __restrict__ dst, const int* __restrict__ src,
    int* __restrict__ cur, int2* __restrict__ tri2,
    const float* __restrict__ node, const float* __restrict__ Wm,
    const float* __restrict__ bm, unsigned short* __restrict__ P)
{
    __shared__ unsigned short sA[PT][136];   // 8704 B (proj branch only)
    const int t = threadIdx.x;

    if (blockIdx.x < SCB) {
        // ---- scatter ----
        int e = blockIdx.x * 256 + t;
        int s = src[e];
        int d = dst[e];
        int p = atomicAdd(&cur[d], 1);
        tri2[p] = make_int2(e, s | (d << 16));
        return;
    }

    // ---- proj ----
    const int n0 = (blockIdx.x - SCB) * PT;
    const int w = t >> 6, lane = t & 63, l15 = lane & 15, lhi = lane >> 4;

    // B fragments in registers: Wn = Wm[:, 0:128)
    bf16x8 bw[4][2];
    #pragma unroll
    for (int bj = 0; bj < 2; ++bj) {
        int n = w * 32 + bj * 16 + l15;
        const float* wp = Wm + n * KM;
        #pragma unroll
        for (int ks = 0; ks < 4; ++ks) {
            float4 x = *(const float4*)(wp + ks * 32 + lhi * 8);
            float4 y = *(const float4*)(wp + ks * 32 + lhi * 8 + 4);
            bw[ks][bj] = pk8(x, y);
        }
    }
    float bmv[2] = { bm[w * 32 + l15], bm[w * 32 + 16 + l15] };

    {
        int el = t >> 3, sub = t & 7;
        const float* np = node + (size_t)(n0 + el) * ND + sub * 16;
        #pragma unroll
        for (int i = 0; i < 4; ++i) {
            float4 v = *(const float4*)(np + i * 4);
            *(us4*)&sA[el][sub * 16 + i * 4] = pk4(v);
        }
    }
    __syncthreads();

    const int koff = lhi * 8;
    f32x4 acc[2][2] = {};
    #pragma unroll
    for (int ks = 0; ks < 4; ++ks) {
        bf16x8 a0 = *(const bf16x8*)&sA[l15][ks * 32 + koff];
        bf16x8 a1 = *(const bf16x8*)&sA[16 + l15][ks * 32 + koff];
        acc[0][0] = __builtin_amdgcn_mfma_f32_16x16x32_bf16(a0, bw[ks][0], acc[0][0], 0, 0, 0);
        acc[1][0] = __builtin_amdgcn_mfma_f32_16x16x32_bf16(a1, bw[ks][0], acc[1][0], 0, 0, 0);
        acc[0][1] = __builtin_amdgcn_mfma_f32_16x16x32_bf16(a0, bw[ks][1], acc[0][1], 0, 0, 0);
        acc[1][1] = __builtin_amdgcn_mfma_f32_16x16x32_bf16(a1, bw[ks][1], acc[1][1], 0, 0, 0);
    }
    #pragma unroll
    for (int ai = 0; ai < 2; ++ai)
        #pragma unroll
        for (int r = 0; r < 4; ++r) {
            int m = n0 + ai * 16 + 4 * lhi + r;
            #pragma unroll
            for (int bj = 0; bj < 2; ++bj) {
                int n = w * 32 + bj * 16 + l15;
                P[(size_t)m * OD + n] = f2bf1(acc[ai][bj][r] + bmv[bj]);
            }
        }
}

// ---------------- fused message + segmented aggregate (slim LDS) ----------
// One 64-edge tile per block. LDS holds only E (aliased with m); P is added
// during segsum via coalesced L2/L3 reads. 19.4 KB LDS -> 8 blocks/CU.
#define QT 64
#define MROW 148

__global__ __launch_bounds__(256, 8) void msgagg_kernel(
    const float* __restrict__ edgef, const int2* __restrict__ tri2,
    const unsigned short* __restrict__ P,
    const float* __restrict__ Wm,
    float* __restrict__ hn)
{
    __shared__ union {
        unsigned short E[QT][72];    // 9216 B
        unsigned short m[QT][MROW];  // 18944 B
    } u;
    __shared__ int sD[QT];
    __shared__ int sS[QT];

    const int t = threadIdx.x, j0 = blockIdx.x * QT;
    const int w = t >> 6, lane = t & 63, l15 = lane & 15, lhi = lane >> 4;
    const int row = t >> 2, s4 = t & 3;

    // B fragments in registers: We = Wm[:, 128:192)
    bf16x8 bw[2][2];
    #pragma unroll
    for (int bj = 0; bj < 2; ++bj) {
        int n = w * 32 + bj * 16 + l15;
        const float* wp = Wm + n * KM + ND;
        #pragma unroll
        for (int ks = 0; ks < 2; ++ks) {
            float4 x = *(const float4*)(wp + ks * 32 + lhi * 8);
            float4 y = *(const float4*)(wp + ks * 32 + lhi * 8 + 4);
            bw[ks][bj] = pk8(x, y);
        }
    }

    // stage: 4 threads per edge row (edgef gather only)
    {
        int2 id = tri2[j0 + row];
        const float* ep = edgef + (size_t)id.x * ED + s4 * 16;
        #pragma unroll
        for (int i = 0; i < 4; ++i) {
            float4 v = *(const float4*)(ep + i * 4);
            *(us4*)&u.E[row][s4 * 16 + i * 4] = pk4(v);
        }
        if (s4 == 0) {
            sS[row] = id.y & 0xFFFF;
            sD[row] = (int)(((unsigned)id.y) >> 16);
        }
    }
    __syncthreads();

    // MFMA: Ge = edge @ We^T
    f32x4 acc[4][2] = {};
    #pragma unroll
    for (int ks = 0; ks < 2; ++ks) {
        bf16x8 a[4];
        #pragma unroll
        for (int ai = 0; ai < 4; ++ai)
            a[ai] = *(const bf16x8*)&u.E[ai * 16 + l15][ks * 32 + lhi * 8];
        #pragma unroll
        for (int ai = 0; ai < 4; ++ai) {
            acc[ai][0] = __builtin_amdgcn_mfma_f32_16x16x32_bf16(a[ai], bw[ks][0], acc[ai][0], 0, 0, 0);
            acc[ai][1] = __builtin_amdgcn_mfma_f32_16x16x32_bf16(a[ai], bw[ks][1], acc[ai][1], 0, 0, 0);
        }
    }
    __syncthreads();   // all E reads complete before m overwrites

    // dump RAW Ge tile to LDS (bf16); P/relu applied in segsum
    #pragma unroll
    for (int ai = 0; ai < 4; ++ai)
        #pragma unroll
        for (int r = 0; r < 4; ++r) {
            int m = ai * 16 + 4 * lhi + r;
            #pragma unroll
            for (int bj = 0; bj < 2; ++bj) {
                int n = w * 32 + bj * 16 + l15;
                u.m[m][n] = f2bf1(acc[ai][bj][r]);
            }
        }
    __syncthreads();

    // segmented sum: 128 threads, one column each; per-row P-add + relu.
    // P[sS[r]] read is a coalesced 256B wave load (L2/L3-served).
    if (t < OD) {
        const int c = t;
        int dprev = sD[0];
        int start = 0;
        float accv = fmaxf(b2f(u.m[0][c]) + b2f(P[(size_t)sS[0] * OD + c]), 0.f);
        #pragma unroll 8
        for (int r = 1; r < QT; ++r) {
            int d = sD[r];                     // wave-uniform broadcast
            float v = fmaxf(b2f(u.m[r][c]) + b2f(P[(size_t)sS[r] * OD + c]), 0.f);
            if (d != dprev) {
                float* dest = hn + (size_t)dprev * OD + c;
                if (start > 0) *dest = accv;   // interior: only this block touches it
                else atomicAdd(dest, accv);
                accv = v; dprev = d; start = r;
            } else {
                accv += v;
            }
        }
        atomicAdd(hn + (size_t)dprev * OD + c, accv);  // last segment: boundary
    }
}

// ---------------- apply: relu([node | h_neigh] @ Wa^T + ba) ----------------
#define AT 32

__global__ __launch_bounds__(256, 3) void apply_kernel(
    const float* __restrict__ node, const float* __restrict__ hn,
    const unsigned short* __restrict__ Wab, const float* __restrict__ ba,
    float* __restrict__ out)
{
    __shared__ unsigned short sA[AT][264];

    const int t  = threadIdx.x;
    const int n0 = blockIdx.x * AT;
    const int w = t >> 6, lane = t & 63, l15 = lane & 15, lhi = lane >> 4;

    bf16x8 bw[8][2];
    #pragma unroll
    for (int bj = 0; bj < 2; ++bj) {
        int n = w * 32 + bj * 16 + l15;
        const unsigned short* wp = Wab + (size_t)n * KA + lhi * 8;
        #pragma unroll
        for (int ks = 0; ks < 8; ++ks)
            bw[ks][bj] = *(const bf16x8*)(wp + ks * 32);
    }
    float bav[2] = { ba[w * 32 + l15], ba[w * 32 + 16 + l15] };

    {
        int el = t >> 3, sub = t & 7;
        const float* np = node + (size_t)(n0 + el) * ND + sub * 16;
        #pragma unroll
        for (int i = 0; i < 4; ++i) {
            float4 v = *(const float4*)(np + i * 4);
            *(us4*)&sA[el][sub * 16 + i * 4] = pk4(v);
        }
        const float* hp = hn + (size_t)(n0 + el) * OD + sub * 16;
        #pragma unroll
        for (int i = 0; i < 4; ++i) {
            float4 v = *(const float4*)(hp + i * 4);
            *(us4*)&sA[el][ND + sub * 16 + i * 4] = pk4(v);
        }
    }
    __syncthreads();

    f32x4 acc[2][2] = {};
    #pragma unroll
    for (int ks = 0; ks < 8; ++ks) {
        bf16x8 a0 = *(const bf16x8*)&sA[l15][ks * 32 + lhi * 8];
        bf16x8 a1 = *(const bf16x8*)&sA[16 + l15][ks * 32 + lhi * 8];
        acc[0][0] = __builtin_amdgcn_mfma_f32_16x16x32_bf16(a0, bw[ks][0], acc[0][0], 0, 0, 0);
        acc[1][0] = __builtin_amdgcn_mfma_f32_16x16x32_bf16(a1, bw[ks][0], acc[1][0], 0, 0, 0);
        acc[0][1] = __builtin_amdgcn_mfma_f32_16x16x32_bf16(a0, bw[ks][1], acc[0][1], 0, 0, 0);
        acc[1][1] = __builtin_amdgcn_mfma_f32_16x16x32_bf16(a1, bw[ks][1], acc[1][1], 0, 0, 0);
    }

    #pragma unroll
    for (int ai = 0; ai < 2; ++ai)
        #pragma unroll
        for (int r = 0; r < 4; ++r) {
            int nd = n0 + ai * 16 + 4 * lhi + r;
            #pragma unroll
            for (int bj = 0; bj < 2; ++bj) {
                int n = w * 32 + bj * 16 + l15;
                float v = acc[ai][bj][r] + bav[bj];
                out[(size_t)nd * OD + n] = v > 0.f ? v : 0.f;
            }
        }
}

// ---------------- fallback path (ws too small) ----------------
#define MT 32
#define LK (KM + 8)
__global__ __launch_bounds__(256, 2) void msg_kernel_atomic(
    const float* __restrict__ node, const float* __restrict__ edgef,
    const int* __restrict__ src, const int* __restrict__ dst,
    const float* __restrict__ Wm, const float* __restrict__ bm,
    float* __restrict__ hn)
{
    __shared__ unsigned short sW[OD][LK];
    __shared__ unsigned short sA[MT][LK];

    const int t  = threadIdx.x;
    const int e0 = blockIdx.x * MT;

    for (int i = t; i < OD * KM / 4; i += 256) {
        int base = i * 4;
        int n = base / KM, k = base % KM;
        float4 w = *(const float4*)(Wm + n * KM + k);
        *(us4*)&sW[n][k] = pk4(w);
    }
    {
        int el = t >> 3, sub = t & 7;
        int s = src[e0 + el];
        const float* np = node + (size_t)s * ND + sub * 16;
        #pragma unroll
        for (int i = 0; i < 4; ++i) {
            float4 v = *(const float4*)(np + i * 4);
            *(us4*)&sA[el][sub * 16 + i * 4] = pk4(v);
        }
        const float* ep = edgef + (size_t)(e0 + el) * ED + sub * 8;
        #pragma unroll
        for (int i = 0; i < 2; ++i) {
            float4 v = *(const float4*)(ep + i * 4);
            *(us4*)&sA[el][ND + sub * 8 + i * 4] = pk4(v);
        }
    }
    __syncthreads();

    const int w = t >> 6, lane = t & 63, l15 = lane & 15, lhi = lane >> 4;
    const int koff = lhi * 8;
    f32x4 acc[2][2] = {};

    #pragma unroll
    for (int ks = 0; ks < 6; ++ks) {
        bf16x8 a0 = *(const bf16x8*)&sA[l15][ks * 32 + koff];
        bf16x8 a1 = *(const bf16x8*)&sA[16 + l15][ks * 32 + koff];
        bf16x8 b0 = *(const bf16x8*)&sW[w * 32 + l15][ks * 32 + koff];
        bf16x8 b1 = *(const bf16x8*)&sW[w * 32 + 16 + l15][ks * 32 + koff];
        acc[0][0] = __builtin_amdgcn_mfma_f32_16x16x32_bf16(a0, b0, acc[0][0], 0, 0, 0);
        acc[1][0] = __builtin_amdgcn_mfma_f32_16x16x32_bf16(a1, b0, acc[1][0], 0, 0, 0);
        acc[0][1] = __builtin_amdgcn_mfma_f32_16x16x32_bf16(a0, b1, acc[0][1], 0, 0, 0);
        acc[1][1] = __builtin_amdgcn_mfma_f32_16x16x32_bf16(a1, b1, acc[1][1], 0, 0, 0);
    }

    #pragma unroll
    for (int ai = 0; ai < 2; ++ai)
        #pragma unroll
        for (int r = 0; r < 4; ++r) {
            int el = ai * 16 + 4 * lhi + r;
            int d  = dst[e0 + el];
            float* hrow = hn + (size_t)d * OD;
            #pragma unroll
            for (int bj = 0; bj < 2; ++bj) {
                int n = w * 32 + bj * 16 + l15;
                float v = acc[ai][bj][r] + bm[n];
                v = v > 0.f ? v : 0.f;
                atomicAdd(hrow + n, v);
            }
        }
}

__global__ __launch_bounds__(256, 2) void apply_legacy_kernel(
    const float* __restrict__ node, const float* __restrict__ hn,
    const float* __restrict__ Wa, const float* __restrict__ ba,
    float* __restrict__ out)
{
    __shared__ unsigned short sW[OD][136];
    __shared__ unsigned short sA[AT][264];

    const int t  = threadIdx.x;
    const int n0 = blockIdx.x * AT;

    {
        int el = t >> 3, sub = t & 7;
        const float* np = node + (size_t)(n0 + el) * ND + sub * 16;
        #pragma unroll
        for (int i = 0; i < 4; ++i) {
            float4 v = *(const float4*)(np + i * 4);
            *(us4*)&sA[el][sub * 16 + i * 4] = pk4(v);
        }
        const float* hp = hn + (size_t)(n0 + el) * OD + sub * 16;
        #pragma unroll
        for (int i = 0; i < 4; ++i) {
            float4 v = *(const float4*)(hp + i * 4);
            *(us4*)&sA[el][ND + sub * 16 + i * 4] = pk4(v);
        }
    }
    for (int i = t; i < OD * 128 / 4; i += 256) {
        int base = i * 4;
        int n = base / 128, k = base % 128;
        float4 w = *(const float4*)(Wa + n * KA + k);
        *(us4*)&sW[n][k] = pk4(w);
    }
    __syncthreads();

    const int w = t >> 6, lane = t & 63, l15 = lane & 15, lhi = lane >> 4;
    const int koff = lhi * 8;
    f32x4 acc[2][2] = {};

    #pragma unroll
    for (int ks = 0; ks < 4; ++ks) {
        bf16x8 a0 = *(const bf16x8*)&sA[l15][ks * 32 + koff];
        bf16x8 a1 = *(const bf16x8*)&sA[16 + l15][ks * 32 + koff];
        bf16x8 b0 = *(const bf16x8*)&sW[w * 32 + l15][ks * 32 + koff];
        bf16x8 b1 = *(const bf16x8*)&sW[w * 32 + 16 + l15][ks * 32 + koff];
        acc[0][0] = __builtin_amdgcn_mfma_f32_16x16x32_bf16(a0, b0, acc[0][0], 0, 0, 0);
        acc[1][0] = __builtin_amdgcn_mfma_f32_16x16x32_bf16(a1, b0, acc[1][0], 0, 0, 0);
        acc[0][1] = __builtin_amdgcn_mfma_f32_16x16x32_bf16(a0, b1, acc[0][1], 0, 0, 0);
        acc[1][1] = __builtin_amdgcn_mfma_f32_16x16x32_bf16(a1, b1, acc[1][1], 0, 0, 0);
    }
    __syncthreads();
    for (int i = t; i < OD * 128 / 4; i += 256) {
        int base = i * 4;
        int n = base / 128, k = base % 128;
        float4 w = *(const float4*)(Wa + n * KA + 128 + k);
        *(us4*)&sW[n][k] = pk4(w);
    }
    __syncthreads();
    #pragma unroll
    for (int ks = 0; ks < 4; ++ks) {
        bf16x8 a0 = *(const bf16x8*)&sA[l15][128 + ks * 32 + koff];
        bf16x8 a1 = *(const bf16x8*)&sA[16 + l15][128 + ks * 32 + koff];
        bf16x8 b0 = *(const bf16x8*)&sW[w * 32 + l15][ks * 32 + koff];
        bf16x8 b1 = *(const bf16x8*)&sW[w * 32 + 16 + l15][ks * 32 + koff];
        acc[0][0] = __builtin_amdgcn_mfma_f32_16x16x32_bf16(a0, b0, acc[0][0], 0, 0, 0);
        acc[1][0] = __builtin_amdgcn_mfma_f32_16x16x32_bf16(a1, b0, acc[1][0], 0, 0, 0);
        acc[0][1] = __builtin_amdgcn_mfma_f32_16x16x32_bf16(a0, b1, acc[0][1], 0, 0, 0);
        acc[1][1] = __builtin_amdgcn_mfma_f32_16x16x32_bf16(a1, b1, acc[1][1], 0, 0, 0);
    }

    #pragma unroll
    for (int ai = 0; ai < 2; ++ai)
        #pragma unroll
        for (int r = 0; r < 4; ++r) {
            int nd = n0 + ai * 16 + 4 * lhi + r;
            #pragma unroll
            for (int bj = 0; bj < 2; ++bj) {
                int n = w * 32 + bj * 16 + l15;
                float v = acc[ai][bj][r] + ba[n];
                out[(size_t)nd * OD + n] = v > 0.f ? v : 0.f;
            }
        }
}

extern "C" void kernel_launch(void* const* d_in, const int* in_sizes, int n_in,
                              void* d_out, int out_size, void* d_ws, size_t ws_size,
                              hipStream_t stream) {
    const float* node  = (const float*)d_in[0];
    const float* edgef = (const float*)d_in[1];
    const int*   src   = (const int*)d_in[2];
    const int*   dst   = (const int*)d_in[3];
    const float* Wm    = (const float*)d_in[4];
    const float* bm    = (const float*)d_in[5];
    const float* Wa    = (const float*)d_in[6];
    const float* ba    = (const float*)d_in[7];
    float* out = (float*)d_out;

    // ws layout
    size_t o = 0;
    const size_t o_P    = o; o += (size_t)NN * OD * 2;      // 10.24 MB
    const size_t o_hn   = o; o += (size_t)NN * OD * 4;      // 20.48 MB
    const size_t o_tri  = o; o += (size_t)NE * 8;           // 5.12 MB
    const size_t o_cur  = o; o += (size_t)NN * 4;           // 160 KB
    const size_t o_bsum = o; o += 64 * 4;
    const size_t o_wab  = o; o += (size_t)OD * KA * 2;      // 64 KB
    const size_t need   = o;                                 // ~36.1 MB

    char* ws = (char*)d_ws;

    if (ws_size >= need) {
        unsigned short* P   = (unsigned short*)(ws + o_P);
        float* hn   = (float*)(ws + o_hn);
        int2*  tri2 = (int2*)(ws + o_tri);
        int*   cur  = (int*)(ws + o_cur);
        int*   bsum = (int*)(ws + o_bsum);
        unsigned short* Wab = (unsigned short*)(ws + o_wab);

        hipMemsetAsync(cur, 0, (size_t)NN * 4, stream);
        hist_kernel<<<(NE + 255) / 256, 256, 0, stream>>>(dst, cur, (float4*)hn);
        scanA_kernel<<<NB, 1024, 0, stream>>>(cur, bsum);
        scanC_kernel<<<NB, 1024, 0, stream>>>(cur, bsum, Wa, Wab);
        scatterproj_kernel<<<SCB + NN / PT, 256, 0, stream>>>(
            dst, src, cur, tri2, node, Wm, bm, P);
        msgagg_kernel<<<NE / QT, 256, 0, stream>>>(edgef, tri2, P, Wm, hn);
        apply_kernel<<<NN / AT, 256, 0, stream>>>(node, hn, Wab, ba, out);
    } else {
        const size_t hn_bytes = (size_t)NN * OD * 4;
        float* hn = (ws_size >= hn_bytes) ? (float*)d_ws : out;
        hipMemsetAsync(hn, 0, hn_bytes, stream);
        msg_kernel_atomic<<<NE / MT, 256, 0, stream>>>(node, edgef, src, dst, Wm, bm, hn);
        apply_legacy_kernel<<<NN / AT, 256, 0, stream>>>(node, hn, Wa, ba, out);
    }
}

// Round 11
// 179.483 us; speedup vs baseline: 1.4734x; 1.4734x over previous
//
#include <hip/hip_runtime.h>
#include <hip/hip_bf16.h>
#include <stdint.h>

#define NN 40000
#define NE 640000
#define ND 128
#define ED 64
#define OD 128
#define KM 192   // ND + ED
#define KA 256   // ND + OD
#define NB 40    // scan blocks (40*1024 >= NN)

typedef __attribute__((ext_vector_type(8))) short bf16x8;
typedef __attribute__((ext_vector_type(4))) float f32x4;
typedef __attribute__((ext_vector_type(4))) unsigned short us4;

__device__ __forceinline__ uint32_t pkbf2(float a, float b) {
    __hip_bfloat162 h = __float22bfloat162_rn(make_float2(a, b));
    union { __hip_bfloat162 h; uint32_t u; } cv; cv.h = h; return cv.u;
}
__device__ __forceinline__ unsigned short f2bf1(float f) {
    __hip_bfloat16 h = __float2bfloat16(f);
    union { __hip_bfloat16 h; unsigned short u; } cv; cv.h = h; return cv.u;
}
__device__ __forceinline__ us4 pk4(float4 v) {
    union { uint2 u; us4 s; } cv;
    cv.u.x = pkbf2(v.x, v.y);
    cv.u.y = pkbf2(v.z, v.w);
    return cv.s;
}
__device__ __forceinline__ bf16x8 pk8(float4 a, float4 b) {
    union { uint4 u; bf16x8 s; } cv;
    cv.u.x = pkbf2(a.x, a.y); cv.u.y = pkbf2(a.z, a.w);
    cv.u.z = pkbf2(b.x, b.y); cv.u.w = pkbf2(b.z, b.w);
    return cv.s;
}
__device__ __forceinline__ float b2f(unsigned short u) {
    union { uint32_t u; float f; } v; v.u = ((uint32_t)u) << 16; return v.f;
}

// ---------------- CSR build ----------------
// hist + zero hn (fused)
__global__ __launch_bounds__(256) void hist_kernel(
    const int* __restrict__ dst, int* __restrict__ cnt, float4* __restrict__ hnz)
{
    int e = blockIdx.x * blockDim.x + threadIdx.x;
    if (e < NE) atomicAdd(&cnt[dst[e]], 1);
    #pragma unroll
    for (int k = 0; k < 2; ++k) {
        int j = e + k * (NE);
        if (j < NN * OD / 4) hnz[j] = make_float4(0.f, 0.f, 0.f, 0.f);
    }
}

// in-place per-block exclusive scan of cur[1024] chunk; bsum[b] = block total
__global__ __launch_bounds__(1024) void scanA_kernel(
    int* __restrict__ cur, int* __restrict__ bsum)
{
    __shared__ int wsum[16];
    const int t = threadIdx.x, b = blockIdx.x;
    const int idx = b * 1024 + t;
    int v = (idx < NN) ? cur[idx] : 0;
    int x = v;
    #pragma unroll
    for (int d = 1; d < 64; d <<= 1) {
        int y = __shfl_up(x, d, 64);
        if ((t & 63) >= d) x += y;
    }
    const int wid = t >> 6;
    if ((t & 63) == 63) wsum[wid] = x;
    __syncthreads();
    if (t < 16) {
        int s = wsum[t];
        #pragma unroll
        for (int d = 1; d < 16; d <<= 1) {
            int y = __shfl_up(s, d, 64);
            if (t >= d) s += y;
        }
        wsum[t] = s;
    }
    __syncthreads();
    int incl = x + (wid > 0 ? wsum[wid - 1] : 0);
    if (idx < NN) cur[idx] = incl - v;
    if (t == 1023) bsum[b] = incl;
}

// add prefix of block sums; ALSO convert Wa -> bf16 (Wab)
__global__ __launch_bounds__(1024) void scanC_kernel(
    int* __restrict__ cur, const int* __restrict__ bsum,
    const float* __restrict__ Wa, unsigned short* __restrict__ Wab)
{
    __shared__ int sboff;
    const int t = threadIdx.x, b = blockIdx.x;
    if (t < 64) {
        int v = (t < b) ? bsum[t] : 0;
        #pragma unroll
        for (int d = 32; d > 0; d >>= 1) v += __shfl_down(v, d, 64);
        if (t == 0) sboff = v;
    }
    const int gidx = b * 1024 + t;
    if (gidx < OD * KA) Wab[gidx] = f2bf1(Wa[gidx]);
    __syncthreads();
    if (gidx < NN) cur[gidx] += sboff;
}

// ---------------- fused scatter + proj (grid-partitioned) ----------------
#define PT 32
#define SCB 2500

__global__ __launch_bounds__(256, 4) void scatterproj_kernel(
    const int* __restrict__ dst, const int* __restrict__ src,
    int* __restrict__ cur, int2* __restrict__ tri2,
    const float* __restrict__ node, const float* __restrict__ Wm,
    const float* __restrict__ bm, unsigned short* __restrict__ P)
{
    __shared__ unsigned short sA[PT][136];
    const int t = threadIdx.x;

    if (blockIdx.x < SCB) {
        int e = blockIdx.x * 256 + t;
        int s = src[e];
        int d = dst[e];
        int p = atomicAdd(&cur[d], 1);
        tri2[p] = make_int2(e, s | (d << 16));
        return;
    }

    const int n0 = (blockIdx.x - SCB) * PT;
    const int w = t >> 6, lane = t & 63, l15 = lane & 15, lhi = lane >> 4;

    bf16x8 bw[4][2];
    #pragma unroll
    for (int bj = 0; bj < 2; ++bj) {
        int n = w * 32 + bj * 16 + l15;
        const float* wp = Wm + n * KM;
        #pragma unroll
        for (int ks = 0; ks < 4; ++ks) {
            float4 x = *(const float4*)(wp + ks * 32 + lhi * 8);
            float4 y = *(const float4*)(wp + ks * 32 + lhi * 8 + 4);
            bw[ks][bj] = pk8(x, y);
        }
    }
    float bmv[2] = { bm[w * 32 + l15], bm[w * 32 + 16 + l15] };

    {
        int el = t >> 3, sub = t & 7;
        const float* np = node + (size_t)(n0 + el) * ND + sub * 16;
        #pragma unroll
        for (int i = 0; i < 4; ++i) {
            float4 v = *(const float4*)(np + i * 4);
            *(us4*)&sA[el][sub * 16 + i * 4] = pk4(v);
        }
    }
    __syncthreads();

    const int koff = lhi * 8;
    f32x4 acc[2][2] = {};
    #pragma unroll
    for (int ks = 0; ks < 4; ++ks) {
        bf16x8 a0 = *(const bf16x8*)&sA[l15][ks * 32 + koff];
        bf16x8 a1 = *(const bf16x8*)&sA[16 + l15][ks * 32 + koff];
        acc[0][0] = __builtin_amdgcn_mfma_f32_16x16x32_bf16(a0, bw[ks][0], acc[0][0], 0, 0, 0);
        acc[1][0] = __builtin_amdgcn_mfma_f32_16x16x32_bf16(a1, bw[ks][0], acc[1][0], 0, 0, 0);
        acc[0][1] = __builtin_amdgcn_mfma_f32_16x16x32_bf16(a0, bw[ks][1], acc[0][1], 0, 0, 0);
        acc[1][1] = __builtin_amdgcn_mfma_f32_16x16x32_bf16(a1, bw[ks][1], acc[1][1], 0, 0, 0);
    }
    #pragma unroll
    for (int ai = 0; ai < 2; ++ai)
        #pragma unroll
        for (int r = 0; r < 4; ++r) {
            int m = n0 + ai * 16 + 4 * lhi + r;
            #pragma unroll
            for (int bj = 0; bj < 2; ++bj) {
                int n = w * 32 + bj * 16 + l15;
                P[(size_t)m * OD + n] = f2bf1(acc[ai][bj][r] + bmv[bj]);
            }
        }
}

// ---------------- fused message + segmented aggregate (slim LDS + RMW P) ---
// One 64-edge tile per block. LDS: E aliased with m (18.9 KB) -> 8 blocks/CU.
// Phases: stage(E) -> MFMA -> dump raw Ge -> RMW (re-gather P from L2,
// relu(Ge+P') in place, coalesced) -> pure-LDS segsum.
#define QT 64
#define MROW 148

__global__ __launch_bounds__(256, 8) void msgagg_kernel(
    const float* __restrict__ edgef, const int2* __restrict__ tri2,
    const unsigned short* __restrict__ P,
    const float* __restrict__ Wm,
    float* __restrict__ hn)
{
    __shared__ union {
        unsigned short E[QT][72];    // 9216 B
        unsigned short m[QT][MROW];  // 18944 B
    } u;
    __shared__ int sD[QT];
    __shared__ int sS[QT];

    const int t = threadIdx.x, j0 = blockIdx.x * QT;
    const int w = t >> 6, lane = t & 63, l15 = lane & 15, lhi = lane >> 4;
    const int row = t >> 2, s4 = t & 3;

    // B fragments in registers: We = Wm[:, 128:192)
    bf16x8 bw[2][2];
    #pragma unroll
    for (int bj = 0; bj < 2; ++bj) {
        int n = w * 32 + bj * 16 + l15;
        const float* wp = Wm + n * KM + ND;
        #pragma unroll
        for (int ks = 0; ks < 2; ++ks) {
            float4 x = *(const float4*)(wp + ks * 32 + lhi * 8);
            float4 y = *(const float4*)(wp + ks * 32 + lhi * 8 + 4);
            bw[ks][bj] = pk8(x, y);
        }
    }

    // stage: 4 threads per edge row (edgef gather only; P deferred to RMW)
    {
        int2 id = tri2[j0 + row];
        const float* ep = edgef + (size_t)id.x * ED + s4 * 16;
        #pragma unroll
        for (int i = 0; i < 4; ++i) {
            float4 v = *(const float4*)(ep + i * 4);
            *(us4*)&u.E[row][s4 * 16 + i * 4] = pk4(v);
        }
        if (s4 == 0) {
            sS[row] = id.y & 0xFFFF;
            sD[row] = (int)(((unsigned)id.y) >> 16);
        }
    }
    __syncthreads();

    // MFMA: Ge = edge @ We^T
    f32x4 acc[4][2] = {};
    #pragma unroll
    for (int ks = 0; ks < 2; ++ks) {
        bf16x8 a[4];
        #pragma unroll
        for (int ai = 0; ai < 4; ++ai)
            a[ai] = *(const bf16x8*)&u.E[ai * 16 + l15][ks * 32 + lhi * 8];
        #pragma unroll
        for (int ai = 0; ai < 4; ++ai) {
            acc[ai][0] = __builtin_amdgcn_mfma_f32_16x16x32_bf16(a[ai], bw[ks][0], acc[ai][0], 0, 0, 0);
            acc[ai][1] = __builtin_amdgcn_mfma_f32_16x16x32_bf16(a[ai], bw[ks][1], acc[ai][1], 0, 0, 0);
        }
    }
    __syncthreads();   // all E reads complete before m overwrites

    // dump RAW Ge tile to LDS (bf16)
    #pragma unroll
    for (int ai = 0; ai < 4; ++ai)
        #pragma unroll
        for (int r = 0; r < 4; ++r) {
            int m = ai * 16 + 4 * lhi + r;
            #pragma unroll
            for (int bj = 0; bj < 2; ++bj) {
                int n = w * 32 + bj * 16 + l15;
                u.m[m][n] = f2bf1(acc[ai][bj][r]);
            }
        }
    __syncthreads();

    // RMW: m[row][c] = relu(Ge + P')  — coalesced 256B/row L2 gather of P
    {
        const uint4* pp = (const uint4*)(P + (size_t)sS[row] * OD) + s4 * 4;
        uint4 pv0 = pp[0], pv1 = pp[1], pv2 = pp[2], pv3 = pp[3];
        uint32_t* mp = (uint32_t*)&u.m[row][s4 * 32];
        const uint4 pv[4] = { pv0, pv1, pv2, pv3 };
        #pragma unroll
        for (int i = 0; i < 4; ++i) {
            #pragma unroll
            for (int j = 0; j < 4; ++j) {
                uint32_t p2 = ((const uint32_t*)&pv[i])[j];
                uint32_t g2 = mp[i * 4 + j];
                float lo = fmaxf(b2f((unsigned short)(g2 & 0xFFFF)) +
                                 b2f((unsigned short)(p2 & 0xFFFF)), 0.f);
                float hi = fmaxf(b2f((unsigned short)(g2 >> 16)) +
                                 b2f((unsigned short)(p2 >> 16)), 0.f);
                mp[i * 4 + j] = pkbf2(lo, hi);
            }
        }
    }
    __syncthreads();

    // segmented sum: 128 threads, one column each; pure LDS (r9 structure)
    if (t < OD) {
        const int c = t;
        int dprev = sD[0];
        int start = 0;
        float accv = b2f(u.m[0][c]);
        #pragma unroll 4
        for (int r = 1; r < QT; ++r) {
            int d = sD[r];                     // wave-uniform broadcast
            float v = b2f(u.m[r][c]);
            if (d != dprev) {
                float* dest = hn + (size_t)dprev * OD + c;
                if (start > 0) *dest = accv;   // interior: only this block touches it
                else atomicAdd(dest, accv);
                accv = v; dprev = d; start = r;
            } else {
                accv += v;
            }
        }
        atomicAdd(hn + (size_t)dprev * OD + c, accv);  // last segment: boundary
    }
}

// ---------------- apply: relu([node | h_neigh] @ Wa^T + ba) ----------------
#define AT 32

__global__ __launch_bounds__(256, 3) void apply_kernel(
    const float* __restrict__ node, const float* __restrict__ hn,
    const unsigned short* __restrict__ Wab, const float* __restrict__ ba,
    float* __restrict__ out)
{
    __shared__ unsigned short sA[AT][264];

    const int t  = threadIdx.x;
    const int n0 = blockIdx.x * AT;
    const int w = t >> 6, lane = t & 63, l15 = lane & 15, lhi = lane >> 4;

    bf16x8 bw[8][2];
    #pragma unroll
    for (int bj = 0; bj < 2; ++bj) {
        int n = w * 32 + bj * 16 + l15;
        const unsigned short* wp = Wab + (size_t)n * KA + lhi * 8;
        #pragma unroll
        for (int ks = 0; ks < 8; ++ks)
            bw[ks][bj] = *(const bf16x8*)(wp + ks * 32);
    }
    float bav[2] = { ba[w * 32 + l15], ba[w * 32 + 16 + l15] };

    {
        int el = t >> 3, sub = t & 7;
        const float* np = node + (size_t)(n0 + el) * ND + sub * 16;
        #pragma unroll
        for (int i = 0; i < 4; ++i) {
            float4 v = *(const float4*)(np + i * 4);
            *(us4*)&sA[el][sub * 16 + i * 4] = pk4(v);
        }
        const float* hp = hn + (size_t)(n0 + el) * OD + sub * 16;
        #pragma unroll
        for (int i = 0; i < 4; ++i) {
            float4 v = *(const float4*)(hp + i * 4);
            *(us4*)&sA[el][ND + sub * 16 + i * 4] = pk4(v);
        }
    }
    __syncthreads();

    f32x4 acc[2][2] = {};
    #pragma unroll
    for (int ks = 0; ks < 8; ++ks) {
        bf16x8 a0 = *(const bf16x8*)&sA[l15][ks * 32 + lhi * 8];
        bf16x8 a1 = *(const bf16x8*)&sA[16 + l15][ks * 32 + lhi * 8];
        acc[0][0] = __builtin_amdgcn_mfma_f32_16x16x32_bf16(a0, bw[ks][0], acc[0][0], 0, 0, 0);
        acc[1][0] = __builtin_amdgcn_mfma_f32_16x16x32_bf16(a1, bw[ks][0], acc[1][0], 0, 0, 0);
        acc[0][1] = __builtin_amdgcn_mfma_f32_16x16x32_bf16(a0, bw[ks][1], acc[0][1], 0, 0, 0);
        acc[1][1] = __builtin_amdgcn_mfma_f32_16x16x32_bf16(a1, bw[ks][1], acc[1][1], 0, 0, 0);
    }

    #pragma unroll
    for (int ai = 0; ai < 2; ++ai)
        #pragma unroll
        for (int r = 0; r < 4; ++r) {
            int nd = n0 + ai * 16 + 4 * lhi + r;
            #pragma unroll
            for (int bj = 0; bj < 2; ++bj) {
                int n = w * 32 + bj * 16 + l15;
                float v = acc[ai][bj][r] + bav[bj];
                out[(size_t)nd * OD + n] = v > 0.f ? v : 0.f;
            }
        }
}

// ---------------- fallback path (ws too small) ----------------
#define MT 32
#define LK (KM + 8)
__global__ __launch_bounds__(256, 2) void msg_kernel_atomic(
    const float* __restrict__ node, const float* __restrict__ edgef,
    const int* __restrict__ src, const int* __restrict__ dst,
    const float* __restrict__ Wm, const float* __restrict__ bm,
    float* __restrict__ hn)
{
    __shared__ unsigned short sW[OD][LK];
    __shared__ unsigned short sA[MT][LK];

    const int t  = threadIdx.x;
    const int e0 = blockIdx.x * MT;

    for (int i = t; i < OD * KM / 4; i += 256) {
        int base = i * 4;
        int n = base / KM, k = base % KM;
        float4 w = *(const float4*)(Wm + n * KM + k);
        *(us4*)&sW[n][k] = pk4(w);
    }
    {
        int el = t >> 3, sub = t & 7;
        int s = src[e0 + el];
        const float* np = node + (size_t)s * ND + sub * 16;
        #pragma unroll
        for (int i = 0; i < 4; ++i) {
            float4 v = *(const float4*)(np + i * 4);
            *(us4*)&sA[el][sub * 16 + i * 4] = pk4(v);
        }
        const float* ep = edgef + (size_t)(e0 + el) * ED + sub * 8;
        #pragma unroll
        for (int i = 0; i < 2; ++i) {
            float4 v = *(const float4*)(ep + i * 4);
            *(us4*)&sA[el][ND + sub * 8 + i * 4] = pk4(v);
        }
    }
    __syncthreads();

    const int w = t >> 6, lane = t & 63, l15 = lane & 15, lhi = lane >> 4;
    const int koff = lhi * 8;
    f32x4 acc[2][2] = {};

    #pragma unroll
    for (int ks = 0; ks < 6; ++ks) {
        bf16x8 a0 = *(const bf16x8*)&sA[l15][ks * 32 + koff];
        bf16x8 a1 = *(const bf16x8*)&sA[16 + l15][ks * 32 + koff];
        bf16x8 b0 = *(const bf16x8*)&sW[w * 32 + l15][ks * 32 + koff];
        bf16x8 b1 = *(const bf16x8*)&sW[w * 32 + 16 + l15][ks * 32 + koff];
        acc[0][0] = __builtin_amdgcn_mfma_f32_16x16x32_bf16(a0, b0, acc[0][0], 0, 0, 0);
        acc[1][0] = __builtin_amdgcn_mfma_f32_16x16x32_bf16(a1, b0, acc[1][0], 0, 0, 0);
        acc[0][1] = __builtin_amdgcn_mfma_f32_16x16x32_bf16(a0, b1, acc[0][1], 0, 0, 0);
        acc[1][1] = __builtin_amdgcn_mfma_f32_16x16x32_bf16(a1, b1, acc[1][1], 0, 0, 0);
    }

    #pragma unroll
    for (int ai = 0; ai < 2; ++ai)
        #pragma unroll
        for (int r = 0; r < 4; ++r) {
            int el = ai * 16 + 4 * lhi + r;
            int d  = dst[e0 + el];
            float* hrow = hn + (size_t)d * OD;
            #pragma unroll
            for (int bj = 0; bj < 2; ++bj) {
                int n = w * 32 + bj * 16 + l15;
                float v = acc[ai][bj][r] + bm[n];
                v = v > 0.f ? v : 0.f;
                atomicAdd(hrow + n, v);
            }
        }
}

__global__ __launch_bounds__(256, 2) void apply_legacy_kernel(
    const float* __restrict__ node, const float* __restrict__ hn,
    const float* __restrict__ Wa, const float* __restrict__ ba,
    float* __restrict__ out)
{
    __shared__ unsigned short sW[OD][136];
    __shared__ unsigned short sA[AT][264];

    const int t  = threadIdx.x;
    const int n0 = blockIdx.x * AT;

    {
        int el = t >> 3, sub = t & 7;
        const float* np = node + (size_t)(n0 + el) * ND + sub * 16;
        #pragma unroll
        for (int i = 0; i < 4; ++i) {
            float4 v = *(const float4*)(np + i * 4);
            *(us4*)&sA[el][sub * 16 + i * 4] = pk4(v);
        }
        const float* hp = hn + (size_t)(n0 + el) * OD + sub * 16;
        #pragma unroll
        for (int i = 0; i < 4; ++i) {
            float4 v = *(const float4*)(hp + i * 4);
            *(us4*)&sA[el][ND + sub * 16 + i * 4] = pk4(v);
        }
    }
    for (int i = t; i < OD * 128 / 4; i += 256) {
        int base = i * 4;
        int n = base / 128, k = base % 128;
        float4 w = *(const float4*)(Wa + n * KA + k);
        *(us4*)&sW[n][k] = pk4(w);
    }
    __syncthreads();

    const int w = t >> 6, lane = t & 63, l15 = lane & 15, lhi = lane >> 4;
    const int koff = lhi * 8;
    f32x4 acc[2][2] = {};

    #pragma unroll
    for (int ks = 0; ks < 4; ++ks) {
        bf16x8 a0 = *(const bf16x8*)&sA[l15][ks * 32 + koff];
        bf16x8 a1 = *(const bf16x8*)&sA[16 + l15][ks * 32 + koff];
        bf16x8 b0 = *(const bf16x8*)&sW[w * 32 + l15][ks * 32 + koff];
        bf16x8 b1 = *(const bf16x8*)&sW[w * 32 + 16 + l15][ks * 32 + koff];
        acc[0][0] = __builtin_amdgcn_mfma_f32_16x16x32_bf16(a0, b0, acc[0][0], 0, 0, 0);
        acc[1][0] = __builtin_amdgcn_mfma_f32_16x16x32_bf16(a1, b0, acc[1][0], 0, 0, 0);
        acc[0][1] = __builtin_amdgcn_mfma_f32_16x16x32_bf16(a0, b1, acc[0][1], 0, 0, 0);
        acc[1][1] = __builtin_amdgcn_mfma_f32_16x16x32_bf16(a1, b1, acc[1][1], 0, 0, 0);
    }
    __syncthreads();
    for (int i = t; i < OD * 128 / 4; i += 256) {
        int base = i * 4;
        int n = base / 128, k = base % 128;
        float4 w = *(const float4*)(Wa + n * KA + 128 + k);
        *(us4*)&sW[n][k] = pk4(w);
    }
    __syncthreads();
    #pragma unroll
    for (int ks = 0; ks < 4; ++ks) {
        bf16x8 a0 = *(const bf16x8*)&sA[l15][128 + ks * 32 + koff];
        bf16x8 a1 = *(const bf16x8*)&sA[16 + l15][128 + ks * 32 + koff];
        bf16x8 b0 = *(const bf16x8*)&sW[w * 32 + l15][ks * 32 + koff];
        bf16x8 b1 = *(const bf16x8*)&sW[w * 32 + 16 + l15][ks * 32 + koff];
        acc[0][0] = __builtin_amdgcn_mfma_f32_16x16x32_bf16(a0, b0, acc[0][0], 0, 0, 0);
        acc[1][0] = __builtin_amdgcn_mfma_f32_16x16x32_bf16(a1, b0, acc[1][0], 0, 0, 0);
        acc[0][1] = __builtin_amdgcn_mfma_f32_16x16x32_bf16(a0, b1, acc[0][1], 0, 0, 0);
        acc[1][1] = __builtin_amdgcn_mfma_f32_16x16x32_bf16(a1, b1, acc[1][1], 0, 0, 0);
    }

    #pragma unroll
    for (int ai = 0; ai < 2; ++ai)
        #pragma unroll
        for (int r = 0; r < 4; ++r) {
            int nd = n0 + ai * 16 + 4 * lhi + r;
            #pragma unroll
            for (int bj = 0; bj < 2; ++bj) {
                int n = w * 32 + bj * 16 + l15;
                float v = acc[ai][bj][r] + ba[n];
                out[(size_t)nd * OD + n] = v > 0.f ? v : 0.f;
            }
        }
}

extern "C" void kernel_launch(void* const* d_in, const int* in_sizes, int n_in,
                              void* d_out, int out_size, void* d_ws, size_t ws_size,
                              hipStream_t stream) {
    const float* node  = (const float*)d_in[0];
    const float* edgef = (const float*)d_in[1];
    const int*   src   = (const int*)d_in[2];
    const int*   dst   = (const int*)d_in[3];
    const float* Wm    = (const float*)d_in[4];
    const float* bm    = (const float*)d_in[5];
    const float* Wa    = (const float*)d_in[6];
    const float* ba    = (const float*)d_in[7];
    float* out = (float*)d_out;

    // ws layout
    size_t o = 0;
    const size_t o_P    = o; o += (size_t)NN * OD * 2;      // 10.24 MB
    const size_t o_hn   = o; o += (size_t)NN * OD * 4;      // 20.48 MB
    const size_t o_tri  = o; o += (size_t)NE * 8;           // 5.12 MB
    const size_t o_cur  = o; o += (size_t)NN * 4;           // 160 KB
    const size_t o_bsum = o; o += 64 * 4;
    const size_t o_wab  = o; o += (size_t)OD * KA * 2;      // 64 KB
    const size_t need   = o;                                 // ~36.1 MB

    char* ws = (char*)d_ws;

    if (ws_size >= need) {
        unsigned short* P   = (unsigned short*)(ws + o_P);
        float* hn   = (float*)(ws + o_hn);
        int2*  tri2 = (int2*)(ws + o_tri);
        int*   cur  = (int*)(ws + o_cur);
        int*   bsum = (int*)(ws + o_bsum);
        unsigned short* Wab = (unsigned short*)(ws + o_wab);

        hipMemsetAsync(cur, 0, (size_t)NN * 4, stream);
        hist_kernel<<<(NE + 255) / 256, 256, 0, stream>>>(dst, cur, (float4*)hn);
        scanA_kernel<<<NB, 1024, 0, stream>>>(cur, bsum);
        scanC_kernel<<<NB, 1024, 0, stream>>>(cur, bsum, Wa, Wab);
        scatterproj_kernel<<<SCB + NN / PT, 256, 0, stream>>>(
            dst, src, cur, tri2, node, Wm, bm, P);
        msgagg_kernel<<<NE / QT, 256, 0, stream>>>(edgef, tri2, P, Wm, hn);
        apply_kernel<<<NN / AT, 256, 0, stream>>>(node, hn, Wab, ba, out);
    } else {
        const size_t hn_bytes = (size_t)NN * OD * 4;
        float* hn = (ws_size >= hn_bytes) ? (float*)d_ws : out;
        hipMemsetAsync(hn, 0, hn_bytes, stream);
        msg_kernel_atomic<<<NE / MT, 256, 0, stream>>>(node, edgef, src, dst, Wm, bm, hn);
        apply_legacy_kernel<<<NN / AT, 256, 0, stream>>>(node, hn, Wa, ba, out);
    }
}